// Round 2
// baseline (1377.027 us; speedup 1.0000x reference)
//
#include <hip/hip_runtime.h>
#include <cstdio>
#include <cstdint>

typedef unsigned short u16;
typedef unsigned int   u32;
typedef __bf16 bf16x8 __attribute__((ext_vector_type(8)));
typedef float  f32x4  __attribute__((ext_vector_type(4)));

#define DEV __device__ __forceinline__

// ---- constants ----
// B=32, S=4096, DIM=768, HEADS=12, DH=64, INNER=768, NKV=1536, NQ=32
// ws layout (bytes, 256-aligned)
constexpr size_t OFF_WKVF = 0;            // 1536*768*2      = 2,359,296  (bf16, B-frag order)
constexpr size_t OFF_QF   = 2359296;      // 49,152 (bf16, A-frag order, pre-scaled 1/8)
constexpr size_t OFF_K    = 2408448;      // 32*12*4096*64*2 = 201,326,592 (bf16 [bh][s][d])
constexpr size_t OFF_V    = 203735040;    // 201,326,592 (bf16 [bh][chunk64][d64][s64])
constexpr size_t OFF_OP   = 405061632;    // 32*12*16*32*64*4 = 50,331,648 (fp32 partial O)
constexpr size_t OFF_MP   = 455393280;    // 786,432
constexpr size_t OFF_LP   = 456179712;    // 786,432
constexpr size_t OFF_PL   = 456966144;    // 32*32*768*4 = 3,145,728 (pooled fp32)
constexpr size_t WS_NEEDED = 460111872;

DEV u16 bfr(float x) {                    // fp32 -> bf16 RNE
  u32 u = __builtin_bit_cast(u32, x);
  u += 0x7fffu + ((u >> 16) & 1u);
  return (u16)(u >> 16);
}
DEV u32 bfpk(float lo, float hi) { return (u32)bfr(lo) | ((u32)bfr(hi) << 16); }

DEV void gload_lds16(const void* g, void* l) {
  __builtin_amdgcn_global_load_lds((const __attribute__((address_space(1))) u32*)g,
                                   (__attribute__((address_space(3))) u32*)l, 16, 0, 0);
}
DEV void ld8(const float* p, float* r) {
  float4 a = *(const float4*)p;
  float4 b = *(const float4*)(p + 4);
  r[0]=a.x; r[1]=a.y; r[2]=a.z; r[3]=a.w; r[4]=b.x; r[5]=b.y; r[6]=b.z; r[7]=b.w;
}

// ---------------- prep: Wkv fp32 [768][1536] -> bf16 B-frag order ----------------
// WkvF chunk(16B) index = (nb*96 + kc)*16 + (n&15), nb=n>>4, kc=k>>3; holds k..k+8 for col n.
__global__ __launch_bounds__(256) void prep_wkv(const float* __restrict__ Wkv, u16* __restrict__ WkvF) {
  __shared__ float tile[64][65];
  const int kb = blockIdx.x, nb0 = blockIdx.y, t = threadIdx.x;
  #pragma unroll
  for (int i = 0; i < 16; ++i) {
    int kl = i*4 + (t >> 6), nl = t & 63;
    tile[kl][nl] = Wkv[(size_t)(kb*64 + kl)*1536 + nb0*64 + nl];
  }
  __syncthreads();
  #pragma unroll
  for (int i = 0; i < 2; ++i) {
    int c = i*256 + t;
    int nl = c >> 3, kcl = c & 7;
    u32 w[4];
    #pragma unroll
    for (int e = 0; e < 4; ++e)
      w[e] = bfpk(tile[kcl*8 + 2*e][nl], tile[kcl*8 + 2*e + 1][nl]);
    int nbg = nb0*4 + (nl >> 4);
    int kcg = kb*8 + kcl;
    size_t chunk = (size_t)(nbg*96 + kcg)*16 + (nl & 15);
    *(uint4*)(WkvF + chunk*8) = make_uint4(w[0], w[1], w[2], w[3]);
  }
}

// ---------------- prep: q = queries@Wq, scaled 1/8, A-frag order per head ----------------
__global__ __launch_bounds__(256) void prep_q(const float* __restrict__ queries,
                                              const float* __restrict__ Wq,
                                              u16* __restrict__ qf) {
  const int h = blockIdx.x, t = threadIdx.x;
  const int d = t & 63, n0 = (t >> 6) * 8;
  float acc[8] = {};
  for (int k = 0; k < 768; ++k) {
    float w = Wq[(size_t)k*768 + h*64 + d];
    #pragma unroll
    for (int i = 0; i < 8; ++i) acc[i] += queries[(n0 + i)*768 + k] * w;
  }
  #pragma unroll
  for (int i = 0; i < 8; ++i) {
    int n = n0 + i;
    size_t off = ((size_t)((h*8 + (d >> 3))*2 + (n >> 4))*16 + (n & 15))*8 + (d & 7);
    qf[off] = bfr(acc[i] * 0.125f);
  }
}

// ---------------- fused LN + KV projection ----------------
// 512 thr (8 waves, 2x4), 64 rows/block. LDS: xb 96KB (XOR-swizzled) + B-tile 32KB x (1+DBUF).
// DBUF=1: double-buffered staging, counted vmcnt, raw s_barrier (no vmcnt(0) drain in loop).
DEV void stage_tile(const u16* __restrict__ WkvF, char* btbuf, int nsub, int kt, int t, int wid) {
  #pragma unroll
  for (int i = 0; i < 4; ++i) {
    const int ci = i*512 + t;
    const int nbl = ci >> 7, kcl = (ci >> 4) & 7, nl = ci & 15;
    const u16* src = WkvF + ((size_t)((nsub*16 + nbl)*96 + (kt*8 + kcl))*16 + nl)*8;
    gload_lds16(src, btbuf + i*8192 + wid*1024);
  }
}

template<int DBUF>
__global__ __launch_bounds__(512) void ln_kv(const float* __restrict__ x,
    const float* __restrict__ gamma, const float* __restrict__ beta,
    const u16* __restrict__ WkvF, u16* __restrict__ k_ws, u16* __restrict__ v_ws) {
  extern __shared__ char smem[];
  char* xb = smem;           // [64 rows][1536 B], chunk16 XOR (row&7)<<4
  char* bt = smem + 98304;   // B-tile buffer(s)
  const int t = threadIdx.x, lane = t & 63, wid = t >> 6;
  const int b = blockIdx.x >> 6, sc2 = blockIdx.x & 63, s0 = sc2 << 6;

  if (DBUF) stage_tile(WkvF, bt, 0, 0, t, wid);   // prefetch first tile under LN

  float ga[8], be[8], ga2[8] = {}, be2[8] = {};
  ld8(gamma + lane*8, ga);
  ld8(beta  + lane*8, be);
  if (lane < 32) { ld8(gamma + 512 + lane*8, ga2); ld8(beta + 512 + lane*8, be2); }

  // ---- LN phase: one wave per row-group (8 rows each) ----
  #pragma unroll
  for (int rr = 0; rr < 8; ++rr) {
    const int r = wid*8 + rr;
    const float* xr = x + (size_t)(b*4096 + s0 + r)*768;
    float xa[8], xc[8] = {};
    ld8(xr + lane*8, xa);
    float s = 0.f, q = 0.f;
    #pragma unroll
    for (int e = 0; e < 8; ++e) { s += xa[e]; q += xa[e]*xa[e]; }
    if (lane < 32) {
      ld8(xr + 512 + lane*8, xc);
      #pragma unroll
      for (int e = 0; e < 8; ++e) { s += xc[e]; q += xc[e]*xc[e]; }
    }
    #pragma unroll
    for (int m = 1; m <= 32; m <<= 1) { s += __shfl_xor(s, m); q += __shfl_xor(q, m); }
    const float mean = s * (1.f/768.f);
    const float rstd = rsqrtf(q * (1.f/768.f) - mean*mean + 1e-5f);
    const int swz = (r & 7) << 4;
    u32 w[4];
    #pragma unroll
    for (int e = 0; e < 4; ++e)
      w[e] = bfpk((xa[2*e]   - mean)*rstd*ga[2*e]   + be[2*e],
                  (xa[2*e+1] - mean)*rstd*ga[2*e+1] + be[2*e+1]);
    *(uint4*)(xb + r*1536 + ((lane*16) ^ swz)) = make_uint4(w[0],w[1],w[2],w[3]);
    if (lane < 32) {
      #pragma unroll
      for (int e = 0; e < 4; ++e)
        w[e] = bfpk((xc[2*e]   - mean)*rstd*ga2[2*e]   + be2[2*e],
                    (xc[2*e+1] - mean)*rstd*ga2[2*e+1] + be2[2*e+1]);
      *(uint4*)(xb + r*1536 + 1024 + ((lane*16) ^ swz)) = make_uint4(w[0],w[1],w[2],w[3]);
    }
  }
  __syncthreads();

  // ---- GEMM: 6 N-subtiles of 256, K in 12 steps of 64 ----
  const int wm = wid >> 2, wn = wid & 3;
  for (int nsub = 0; nsub < 6; ++nsub) {
    f32x4 acc[2][4] = {};
    for (int kt = 0; kt < 12; ++kt) {
      const char* btr;
      if (DBUF) {
        int kt2 = kt + 1, ns2 = nsub;
        if (kt2 == 12) { kt2 = 0; ns2 = nsub + 1; if (ns2 == 6) ns2 = 0; }
        stage_tile(WkvF, bt + (((kt + 1) & 1) << 15), ns2, kt2, t, wid);
        btr = bt + ((kt & 1) << 15);
      } else {
        __syncthreads();
        stage_tile(WkvF, bt, nsub, kt, t, wid);
        btr = bt;
      }
      // A-fragments from xb (stable) — issue before the wait to overlap
      bf16x8 af[2][2];
      #pragma unroll
      for (int mi = 0; mi < 2; ++mi)
        #pragma unroll
        for (int kk = 0; kk < 2; ++kk) {
          const int row = wm*32 + mi*16 + (lane & 15);
          const int kbyte = kt*128 + kk*64 + ((lane >> 4) << 4);
          af[mi][kk] = *(const bf16x8*)(xb + row*1536 + (kbyte ^ ((row & 7) << 4)));
        }
      if (DBUF) {
        if (kt == 0 && nsub != 0) asm volatile("s_waitcnt vmcnt(8)" ::: "memory");
        else                      asm volatile("s_waitcnt vmcnt(4)" ::: "memory");
        __builtin_amdgcn_s_barrier();
      } else {
        asm volatile("s_waitcnt vmcnt(0)" ::: "memory");
        __syncthreads();
      }
      bf16x8 bw[4][2];
      #pragma unroll
      for (int ni = 0; ni < 4; ++ni)
        #pragma unroll
        for (int kk = 0; kk < 2; ++kk) {
          const int chunk = (wn*4 + ni)*128 + (kk*4 + (lane >> 4))*16 + (lane & 15);
          bw[ni][kk] = *(const bf16x8*)(btr + chunk*16);
        }
      __builtin_amdgcn_s_setprio(1);
      #pragma unroll
      for (int mi = 0; mi < 2; ++mi)
        #pragma unroll
        for (int ni = 0; ni < 4; ++ni) {
          acc[mi][ni] = __builtin_amdgcn_mfma_f32_16x16x32_bf16(af[mi][0], bw[ni][0], acc[mi][ni], 0,0,0);
          acc[mi][ni] = __builtin_amdgcn_mfma_f32_16x16x32_bf16(af[mi][1], bw[ni][1], acc[mi][ni], 0,0,0);
        }
      __builtin_amdgcn_s_setprio(0);
      if (DBUF) {
        asm volatile("s_waitcnt lgkmcnt(0)" ::: "memory");
        __builtin_amdgcn_s_barrier();
      }
    }
    // ---- epilogue: repack acc via free LDS buffer ----
    char* rb = DBUF ? (bt + 32768) : bt;   // DBUF: buf1 free (next stage went to buf0)
    if (!DBUF) __syncthreads();
    if (nsub < 3) {
      // K-part: repack to plain [s][d] rows (swizzled in LDS, linear in global)
      #pragma unroll
      for (int mi = 0; mi < 2; ++mi)
        #pragma unroll
        for (int ni = 0; ni < 4; ++ni)
          #pragma unroll
          for (int j = 0; j < 4; ++j) {
            const int sl = wm*32 + mi*16 + ((lane >> 4) << 2) + j;
            const int dd = ni*16 + (lane & 15);
            *(u16*)(rb + wn*8192 + sl*128 + ((dd*2) ^ ((sl & 7) << 4))) = bfr(acc[mi][ni][j]);
          }
      if (DBUF) { asm volatile("s_waitcnt lgkmcnt(0)" ::: "memory"); __builtin_amdgcn_s_barrier(); }
      else __syncthreads();
      #pragma unroll
      for (int i = 0; i < 4; ++i) {
        const int ci = i*512 + t;
        const int hl = ci >> 9, sl = (ci >> 3) & 63, cc = ci & 7;
        uint4 vd = *(const uint4*)(rb + hl*8192 + sl*128 + ((cc*16) ^ ((sl & 7) << 4)));
        *(uint4*)(k_ws + ((size_t)(b*12 + nsub*4 + hl)*4096 + s0 + sl)*64 + cc*8) = vd;
      }
    } else {
      // V-part: repack transposed [d][s] per 64-chunk
      #pragma unroll
      for (int mi = 0; mi < 2; ++mi)
        #pragma unroll
        for (int ni = 0; ni < 4; ++ni)
          #pragma unroll
          for (int j = 0; j < 4; ++j) {
            const int sl = wm*32 + mi*16 + ((lane >> 4) << 2) + j;
            const int dd = ni*16 + (lane & 15);
            *(u16*)(rb + wn*8192 + dd*128 + ((sl*2) ^ ((dd & 7) << 4))) = bfr(acc[mi][ni][j]);
          }
      if (DBUF) { asm volatile("s_waitcnt lgkmcnt(0)" ::: "memory"); __builtin_amdgcn_s_barrier(); }
      else __syncthreads();
      #pragma unroll
      for (int i = 0; i < 4; ++i) {
        const int ci = i*512 + t;
        const int hl = ci >> 9, dl = (ci >> 3) & 63, cc = ci & 7;
        uint4 vd = *(const uint4*)(rb + hl*8192 + dl*128 + ((cc*16) ^ ((dl & 7) << 4)));
        const int h = (nsub - 3)*4 + hl;
        *(uint4*)(v_ws + (((size_t)(b*12 + h)*64 + sc2)*64 + dl)*64 + cc*8) = vd;
      }
    }
    if (DBUF) {   // repack reads must complete before next nsub's stage overwrites buf1
      asm volatile("s_waitcnt lgkmcnt(0)" ::: "memory");
      __builtin_amdgcn_s_barrier();
    }
  }
}

// ---------------- flash attention partials ----------------
// block = (bh, quarter); wave owns 256 keys. Swapped QK^T: mfma(K,Q) -> scores^T.
__global__ __launch_bounds__(256) void attn(const u16* __restrict__ qf,
    const u16* __restrict__ kw, const u16* __restrict__ vw,
    float* __restrict__ op, float* __restrict__ mp, float* __restrict__ lp) {
  __shared__ __align__(16) char pb[4*2560];
  const int t = threadIdx.x, lane = t & 63, wid = t >> 6;
  const int bh = blockIdx.x >> 2, qc = blockIdx.x & 3;
  const int chunk = qc*4 + wid;
  const int h = bh % 12;
  const u16* kpl = kw + (size_t)bh*4096*64;
  const u16* vpl = vw + (size_t)bh*4096*64;
  char* pbw = pb + wid*2560;               // [32 n][80 B] wave-private P buffer
  const int lo = lane & 15, g = lane >> 4;

  bf16x8 aq[2][2];
  #pragma unroll
  for (int nb = 0; nb < 2; ++nb)
    #pragma unroll
    for (int dk = 0; dk < 2; ++dk)
      aq[nb][dk] = *(const bf16x8*)(qf + ((size_t)((h*8 + dk*4 + g)*2 + nb)*16 + lo)*8);

  float mr[2] = {-1e30f, -1e30f}, lr[2] = {0.f, 0.f};
  f32x4 o[2][4] = {};
  const f32x4 z4 = {};

  for (int w = 0; w < 8; ++w) {
    const int ks = chunk*256 + w*32;
    bf16x8 kf[2][2];
    #pragma unroll
    for (int sb = 0; sb < 2; ++sb)
      #pragma unroll
      for (int dk = 0; dk < 2; ++dk)
        kf[sb][dk] = *(const bf16x8*)(kpl + (size_t)(ks + sb*16 + lo)*64 + dk*32 + g*8);
    f32x4 sc[2][2];
    #pragma unroll
    for (int sb = 0; sb < 2; ++sb)
      #pragma unroll
      for (int nb = 0; nb < 2; ++nb) {
        f32x4 c0 = __builtin_amdgcn_mfma_f32_16x16x32_bf16(kf[sb][0], aq[nb][0], z4, 0,0,0);
        sc[sb][nb] = __builtin_amdgcn_mfma_f32_16x16x32_bf16(kf[sb][1], aq[nb][1], c0, 0,0,0);
      }
    float scale[2];
    #pragma unroll
    for (int nb = 0; nb < 2; ++nb) {
      float pm = sc[0][nb][0];
      #pragma unroll
      for (int sb = 0; sb < 2; ++sb)
        #pragma unroll
        for (int j = 0; j < 4; ++j) pm = fmaxf(pm, sc[sb][nb][j]);
      pm = fmaxf(pm, __shfl_xor(pm, 16));
      pm = fmaxf(pm, __shfl_xor(pm, 32));
      const float mn = fmaxf(mr[nb], pm);
      scale[nb] = __expf(mr[nb] - mn);
      mr[nb] = mn;
      float ps = 0.f;
      #pragma unroll
      for (int sb = 0; sb < 2; ++sb) {
        float p0 = __expf(sc[sb][nb][0] - mn);
        float p1 = __expf(sc[sb][nb][1] - mn);
        float p2 = __expf(sc[sb][nb][2] - mn);
        float p3 = __expf(sc[sb][nb][3] - mn);
        ps += (p0 + p1) + (p2 + p3);
        *(uint2*)(pbw + (nb*16 + lo)*80 + sb*32 + g*8) = make_uint2(bfpk(p0,p1), bfpk(p2,p3));
      }
      ps += __shfl_xor(ps, 16);
      ps += __shfl_xor(ps, 32);
      lr[nb] = lr[nb]*scale[nb] + ps;
    }
    #pragma unroll
    for (int nb = 0; nb < 2; ++nb)
      #pragma unroll
      for (int j = 0; j < 4; ++j) {
        const float sj = __shfl(scale[nb], g*4 + j);
        #pragma unroll
        for (int dt = 0; dt < 4; ++dt) o[nb][dt][j] *= sj;
      }
    asm volatile("s_waitcnt lgkmcnt(0)" ::: "memory");
    bf16x8 ap[2];
    #pragma unroll
    for (int nb = 0; nb < 2; ++nb)
      ap[nb] = *(const bf16x8*)(pbw + (nb*16 + lo)*80 + g*16);
    bf16x8 vf[4];
    const int vch = ks >> 6, sin = ks & 63;
    #pragma unroll
    for (int dt = 0; dt < 4; ++dt)
      vf[dt] = *(const bf16x8*)(vpl + ((size_t)vch*64 + dt*16 + lo)*64 + sin + g*8);
    #pragma unroll
    for (int nb = 0; nb < 2; ++nb)
      #pragma unroll
      for (int dt = 0; dt < 4; ++dt)
        o[nb][dt] = __builtin_amdgcn_mfma_f32_16x16x32_bf16(ap[nb], vf[dt], o[nb][dt], 0,0,0);
  }
  float* ob = op + ((size_t)bh*16 + chunk)*2048;
  #pragma unroll
  for (int nb = 0; nb < 2; ++nb)
    #pragma unroll
    for (int dt = 0; dt < 4; ++dt)
      #pragma unroll
      for (int j = 0; j < 4; ++j)
        ob[(nb*16 + g*4 + j)*64 + dt*16 + lo] = o[nb][dt][j];
  if (g == 0) {
    #pragma unroll
    for (int nb = 0; nb < 2; ++nb) {
      mp[(bh*16 + chunk)*32 + nb*16 + lane] = mr[nb];
      lp[(bh*16 + chunk)*32 + nb*16 + lane] = lr[nb];
    }
  }
}

// ---------------- combine chunk partials -> pooled ----------------
__global__ __launch_bounds__(256) void combine(const float* __restrict__ op,
    const float* __restrict__ mp, const float* __restrict__ lp, float* __restrict__ pooled) {
  __shared__ float f[16][32];
  const int bh = blockIdx.x, t = threadIdx.x;
  if (t < 32) {
    float mg = -1e30f;
    #pragma unroll
    for (int c = 0; c < 16; ++c) mg = fmaxf(mg, mp[(bh*16 + c)*32 + t]);
    float Lg = 0.f;
    #pragma unroll
    for (int c = 0; c < 16; ++c) Lg += lp[(bh*16 + c)*32 + t] * __expf(mp[(bh*16 + c)*32 + t] - mg);
    const float inv = 1.f / Lg;
    #pragma unroll
    for (int c = 0; c < 16; ++c) f[c][t] = __expf(mp[(bh*16 + c)*32 + t] - mg) * inv;
  }
  __syncthreads();
  const int n = t >> 3, dg = (t & 7) * 8;
  float a[8] = {};
  for (int c = 0; c < 16; ++c) {
    const float* o = op + ((size_t)(bh*16 + c)*32 + n)*64 + dg;
    const float fc = f[c][n];
    float4 u = *(const float4*)o, v = *(const float4*)(o + 4);
    a[0] += fc*u.x; a[1] += fc*u.y; a[2] += fc*u.z; a[3] += fc*u.w;
    a[4] += fc*v.x; a[5] += fc*v.y; a[6] += fc*v.z; a[7] += fc*v.w;
  }
  const int b = bh / 12, h = bh % 12;
  float* dst = pooled + (size_t)(b*32 + n)*768 + h*64 + dg;
  *(float4*)dst       = make_float4(a[0],a[1],a[2],a[3]);
  *(float4*)(dst + 4) = make_float4(a[4],a[5],a[6],a[7]);
}

// ---------------- final projection: pooled (1024x768) @ Wo (768x768), fp32 ----------------
__global__ __launch_bounds__(256) void proj(const float* __restrict__ pooled,
    const float* __restrict__ Wo, float* __restrict__ out) {
  __shared__ float At[64][33];
  __shared__ float Bt[32][65];
  const int m0 = blockIdx.x*64, n0 = blockIdx.y*64, t = threadIdx.x;
  const int tr = (t >> 4)*4, tc = (t & 15)*4;
  float acc[4][4] = {};
  for (int k0 = 0; k0 < 768; k0 += 32) {
    __syncthreads();
    #pragma unroll
    for (int i = 0; i < 8; ++i) {
      const int idx = i*256 + t;
      At[idx >> 5][idx & 31] = pooled[(size_t)(m0 + (idx >> 5))*768 + k0 + (idx & 31)];
    }
    #pragma unroll
    for (int i = 0; i < 8; ++i) {
      const int idx = i*256 + t;
      Bt[idx >> 6][idx & 63] = Wo[(size_t)(k0 + (idx >> 6))*768 + n0 + (idx & 63)];
    }
    __syncthreads();
    #pragma unroll
    for (int k = 0; k < 32; ++k) {
      float av[4], bv[4];
      #pragma unroll
      for (int i = 0; i < 4; ++i) av[i] = At[tr + i][k];
      #pragma unroll
      for (int j = 0; j < 4; ++j) bv[j] = Bt[k][tc + j];
      #pragma unroll
      for (int i = 0; i < 4; ++i)
        #pragma unroll
        for (int j = 0; j < 4; ++j) acc[i][j] += av[i]*bv[j];
    }
  }
  #pragma unroll
  for (int i = 0; i < 4; ++i)
    #pragma unroll
    for (int j = 0; j < 4; ++j)
      out[(size_t)(m0 + tr + i)*768 + n0 + tc + j] = acc[i][j];
}

extern "C" void kernel_launch(void* const* d_in, const int* in_sizes, int n_in,
                              void* d_out, int out_size, void* d_ws, size_t ws_size,
                              hipStream_t stream) {
  const float* x    = (const float*)d_in[0];
  const float* qy   = (const float*)d_in[1];
  const float* Wq   = (const float*)d_in[2];
  const float* Wkv  = (const float*)d_in[3];
  const float* Wo   = (const float*)d_in[4];
  const float* gm   = (const float*)d_in[5];
  const float* bet  = (const float*)d_in[6];
  float* out = (float*)d_out;
  char* ws = (char*)d_ws;
  if (ws_size < WS_NEEDED)
    fprintf(stderr, "[AttentionPooler] ws too small: %zu < %zu\n", ws_size, (size_t)WS_NEEDED);

  u16* WkvF  = (u16*)(ws + OFF_WKVF);
  u16* qfrag = (u16*)(ws + OFF_QF);
  u16* kw    = (u16*)(ws + OFF_K);
  u16* vw    = (u16*)(ws + OFF_V);
  float* op  = (float*)(ws + OFF_OP);
  float* mp  = (float*)(ws + OFF_MP);
  float* lp  = (float*)(ws + OFF_LP);
  float* pl  = (float*)(ws + OFF_PL);

  prep_wkv<<<dim3(12, 24), 256, 0, stream>>>(Wkv, WkvF);
  prep_q  <<<12, 256, 0, stream>>>(qy, Wq, qfrag);

  // 160KB LDS (96KB x_ln + 2x32KB dbuf) if the device allows; else 128KB single-buffer.
  hipError_t eb = hipFuncSetAttribute((const void*)ln_kv<1>,
                                      hipFuncAttributeMaxDynamicSharedMemorySize, 163840);
  (void)hipGetLastError();   // clear sticky error if the 160KB opt-in was refused
  if (eb == hipSuccess) {
    ln_kv<1><<<2048, 512, 163840, stream>>>(x, gm, bet, WkvF, kw, vw);
  } else {
    hipFuncSetAttribute((const void*)ln_kv<0>,
                        hipFuncAttributeMaxDynamicSharedMemorySize, 131072);
    ln_kv<0><<<2048, 512, 131072, stream>>>(x, gm, bet, WkvF, kw, vw);
  }

  attn    <<<1536, 256, 0, stream>>>(qfrag, kw, vw, op, mp, lp);
  combine <<<384, 256, 0, stream>>>(op, mp, lp, pl);
  proj    <<<dim3(16, 12), 256, 0, stream>>>(pl, Wo, out);
}